// Round 8
// baseline (365.311 us; speedup 1.0000x reference)
//
#include <hip/hip_runtime.h>
#include <hip/hip_bf16.h>

// Problem constants (CausalSelfAttention): D_MODEL=1024, H=16, Dh=64, B=4, T=2048
#define T_SEQ   2048
#define HEADS   16
#define DH      64
#define DMODEL  1024
#define EQKV    3072   // 3*H*Dh

typedef __attribute__((ext_vector_type(8)))  __bf16 bf16x8;
typedef __attribute__((ext_vector_type(4)))  float  f32x4;
typedef __attribute__((ext_vector_type(16))) float  f32x16;
typedef unsigned short ushort_t;
typedef unsigned int   uint_t;

__device__ __forceinline__ ushort_t f2bfu(float x) {
    union { float f; uint_t u; } c; c.f = x;
    uint_t u = c.u;
    uint_t r = (u + 0x7fffu + ((u >> 16) & 1u)) >> 16;
    return (ushort_t)r;
}

// pack 2 f32 -> u32 holding 2 bf16 (lo = first arg)
__device__ __forceinline__ uint_t cvtpk(float lo, float hi) {
    uint_t r;
    asm volatile("v_cvt_pk_bf16_f32 %0, %1, %2" : "=v"(r) : "v"(lo), "v"(hi));
    return r;
}

// async global->LDS, 16B per lane; LDS dest is wave-uniform base + lane*16
__device__ __forceinline__ void gload16(const ushort_t* g, ushort_t* l) {
    __builtin_amdgcn_global_load_lds(
        (const __attribute__((address_space(1))) void*)g,
        (__attribute__((address_space(3))) void*)l,
        16, 0, 0);
}

// ---------------------------------------------------------------------------
// fp32 -> bf16 conversion (vectorized float4 in, 4 bf16 out)
// ---------------------------------------------------------------------------
__global__ void cvt_f32_bf16(const float* __restrict__ in, ushort_t* __restrict__ out, int n4) {
    int i = blockIdx.x * blockDim.x + threadIdx.x;
    if (i >= n4) return;
    const float4 v = ((const float4*)in)[i];
    ushort_t r0 = f2bfu(v.x), r1 = f2bfu(v.y), r2 = f2bfu(v.z), r3 = f2bfu(v.w);
    uint_t lo = (uint_t)r0 | ((uint_t)r1 << 16);
    uint_t hi = (uint_t)r2 | ((uint_t)r3 << 16);
    ((uint2*)out)[i] = make_uint2(lo, hi);
}

// ---------------------------------------------------------------------------
// bf16 GEMM: C[M][N] = A[M][K] * Bt[N][K]^T   (row-major bf16 raw ushort)
// 128x128 tile, BK=32, 4 waves (2x2), each wave 64x64 (4x4 16x16x32 frags).
// global_load_lds width-16 staging into linear [128][32] LDS (m97 structure).
// NEW: XCD-chunked block swizzle (T1) — requires nwg % 8 == 0 (true for both
// launches: 1536 and 512) so consecutive A-panel-sharing blocks co-reside
// on one XCD's L2.
// ---------------------------------------------------------------------------
#define BM 128
#define BN 128
#define BK 32

template<bool OUT_BF16>
__global__ __launch_bounds__(256) void gemm_bt(const ushort_t* __restrict__ A,
                                               const ushort_t* __restrict__ Bt,
                                               void* __restrict__ Cv,
                                               int M, int N, int K) {
    __shared__ __align__(16) ushort_t As[BM * BK];   // linear row-major 128x32
    __shared__ __align__(16) ushort_t Bs[BN * BK];

    const int tid  = threadIdx.x;
    const int gx   = gridDim.x;
    int flat = blockIdx.y * gx + blockIdx.x;
    const int nwg  = gx * gridDim.y;
    flat = (flat & 7) * (nwg >> 3) + (flat >> 3);   // XCD-chunked, bijective (nwg%8==0)
    const int bn   = flat % gx, bm = flat / gx;
    const int row0 = bm * BM, col0 = bn * BN;
    const int wid  = tid >> 6, lane = tid & 63;
    const int wr   = wid >> 1, wc = wid & 1;
    const int lr   = lane & 15, lg = lane >> 4;

    const int lrow = lane >> 2;           // 0..15 within 16-row chunk
    const int lcol = (lane & 3) * 8;      // 0,8,16,24

    f32x4 acc[4][4] = {};

    for (int k0 = 0; k0 < K; k0 += BK) {
        #pragma unroll
        for (int it = 0; it < 2; ++it) {
            const int c = wid * 2 + it;                     // 0..7
            const int r = c * 16 + lrow;
            gload16(&A [(size_t)(row0 + r) * K + k0 + lcol], &As[c * 512]);
            gload16(&Bt[(size_t)(col0 + r) * K + k0 + lcol], &Bs[c * 512]);
        }
        __syncthreads();

        bf16x8 bfr[4];
        #pragma unroll
        for (int n = 0; n < 4; ++n)
            bfr[n] = *(const bf16x8*)&Bs[(wc * 64 + n * 16 + lr) * BK + lg * 8];
        #pragma unroll
        for (int m = 0; m < 4; ++m) {
            bf16x8 a = *(const bf16x8*)&As[(wr * 64 + m * 16 + lr) * BK + lg * 8];
            #pragma unroll
            for (int n = 0; n < 4; ++n)
                acc[m][n] = __builtin_amdgcn_mfma_f32_16x16x32_bf16(a, bfr[n], acc[m][n], 0, 0, 0);
        }
        __syncthreads();
    }

    #pragma unroll
    for (int m = 0; m < 4; ++m) {
        int rowb = row0 + wr * 64 + m * 16 + lg * 4;
        #pragma unroll
        for (int n = 0; n < 4; ++n) {
            int col = col0 + wc * 64 + n * 16 + lr;
            #pragma unroll
            for (int i = 0; i < 4; ++i) {
                if (OUT_BF16)
                    ((ushort_t*)Cv)[(size_t)(rowb + i) * N + col] = f2bfu(acc[m][n][i]);
                else
                    ((float*)Cv)[(size_t)(rowb + i) * N + col] = acc[m][n][i];
            }
        }
    }
}

// ---------------------------------------------------------------------------
// Causal flash attention, swapped-QK^T 32x32x16 structure.
// One block = 64 q rows of one (b,h); 2 waves x 32 q rows. KV tiles of 64.
// Block remap (proven round 6): each CU hosts one (b,h) (KV L2-resident),
// balanced bx set per CU.
// NEW (round 8): K never touches LDS — each lane loads its QK^T A-fragments
// directly from global/L2 (row i / 32+i per lane, same addressing as the
// proven qf load). Kills the Ks bank-conflict path, halves LDS to 18.4KB,
// shrinks live staging registers. Q pre-scaled by 0.125 (exact in bf16).
// Vt remains double-buffered + XOR-swizzled in LDS. One barrier per tile.
// ---------------------------------------------------------------------------
__global__ __launch_bounds__(128, 3) void attn_fwd(const ushort_t* __restrict__ qkv,
                                                   ushort_t* __restrict__ y) {
    const int flat = blockIdx.x;
    const int xcd  = flat & 7;
    const int s    = flat >> 3;              // 0..255
    const int bh   = xcd * 8 + (s & 7);      // 0..63  (b*16+h)
    const int bx   = 31 - (s >> 3);          // heavy-first within CU
    const int b    = bh >> 4, h = bh & 15;
    const int tid  = threadIdx.x, lane = tid & 63;
    const int wid  = tid >> 6;
    const int i    = lane & 31;              // q column within warp tile
    const int hh   = lane >> 5;              // k-half selector
    const int bT   = b * T_SEQ;

    __shared__ __align__(16) ushort_t Vt[2][64][72];   // [buf][dh][kv] XOR-swizzled

    const int q0 = bx * 64 + wid * 32;
    const int qg = q0 + i;

    // Q B-fragments: col=q (lane&31), k=dh = kd*16 + hh*8 + j ; pre-scaled 1/8
    bf16x8 qf[4];
    {
        const ushort_t* qrow = qkv + (size_t)(bT + qg) * EQKV + h * DH;
        #pragma unroll
        for (int kd = 0; kd < 4; ++kd) {
            bf16x8 q = *(const bf16x8*)&qrow[kd * 16 + hh * 8];
            #pragma unroll
            for (int j = 0; j < 8; ++j)
                ((ushort_t*)&q)[j] = f2bfu(__bfloat162float(
                    *(const __hip_bfloat16*)&((ushort_t*)&q)[j]) * 0.125f);
            qf[kd] = q;
        }
    }

    float m = -1e30f, lsum = 0.f;
    f32x16 o0 = {}, o1 = {};

    const int nt = bx + 1;                   // kv tiles 0..bx

    // ---- stage V tile 0 into buffer 0 (128 threads: 4 chunks each) ----
    #pragma unroll
    for (int it = 0; it < 4; ++it) {
        const int idx = tid + it * 128;      // 0..511
        const int r   = idx >> 3;            // 0..63
        const int cc  = (idx & 7) * 8;       // 0..56
        const size_t go = (size_t)(bT + r) * EQKV + h * DH + cc;
        uint4 vv = *(const uint4*)&qkv[go + 2048];
        const ushort_t* vs = (const ushort_t*)&vv;
        const int chunk = r >> 3, br = r & 7;
        #pragma unroll
        for (int j = 0; j < 8; ++j) {
            int dh = cc + j;
            Vt[0][dh][((chunk ^ (dh >> 3)) << 3) | br] = vs[j];
        }
    }
    __syncthreads();

    for (int t = 0; t < nt; ++t) {
        const int cb = t & 1, nb = cb ^ 1;
        const bool has_next = (t + 1 < nt);
        const int kmin = t * 64;

        // ---- K fragments direct from global/L2 (A-operand rows i, 32+i) ----
        bf16x8 ka0[4], ka1[4];
        {
            const ushort_t* kbase = qkv + (size_t)(bT + kmin) * EQKV + 1024 + h * DH;
            const ushort_t* k0p = kbase + (size_t)i * EQKV + hh * 8;
            const ushort_t* k1p = kbase + (size_t)(32 + i) * EQKV + hh * 8;
            #pragma unroll
            for (int kd = 0; kd < 4; ++kd) {
                ka0[kd] = *(const bf16x8*)&k0p[kd * 16];
                ka1[kd] = *(const bf16x8*)&k1p[kd * 16];
            }
        }

        // ---- issue next V tile's global loads (latency covered by QK^T+softmax)
        uint4 vr[4];
        if (has_next) {
            #pragma unroll
            for (int it = 0; it < 4; ++it) {
                const int idx = tid + it * 128;
                const int r   = idx >> 3;
                const int cc  = (idx & 7) * 8;
                const size_t go = (size_t)(bT + (t + 1) * 64 + r) * EQKV + h * DH + cc;
                vr[it] = *(const uint4*)&qkv[go + 2048];
            }
        }

        const bool needmask = (kmin + 63) > q0;

        // ---- S^T = K * Q^T : two 32-kv groups, K-dim = dh (4 slices) ----
        f32x16 st[2] = {};
        __builtin_amdgcn_s_setprio(1);
        #pragma unroll
        for (int kd = 0; kd < 4; ++kd) {
            st[0] = __builtin_amdgcn_mfma_f32_32x32x16_bf16(ka0[kd], qf[kd], st[0], 0, 0, 0);
            st[1] = __builtin_amdgcn_mfma_f32_32x32x16_bf16(ka1[kd], qf[kd], st[1], 0, 0, 0);
        }
        __builtin_amdgcn_s_setprio(0);

        // ---- mask + row max (own half; partner half via shfl_xor 32) ----
        float pm = -1e30f;
        #pragma unroll
        for (int g = 0; g < 2; ++g) {
            #pragma unroll
            for (int r = 0; r < 16; ++r) {
                float v = st[g][r];
                if (needmask) {
                    int kv = kmin + g * 32 + (r & 3) + 8 * (r >> 2) + 4 * hh;
                    v = (kv <= qg) ? v : -1e30f;
                    st[g][r] = v;
                }
                pm = fmaxf(pm, v);
            }
        }
        pm = fmaxf(pm, __shfl_xor(pm, 32));

        // ---- online softmax with defer-max (T13); scale pre-folded into Q ----
        if (!__all(pm - m <= 8.f)) {
            const float mnew = fmaxf(m, pm);
            const float corr = __expf(m - mnew);
            m = mnew;
            lsum *= corr;
            #pragma unroll
            for (int r = 0; r < 16; ++r) { o0[r] *= corr; o1[r] *= corr; }
        }
        float rs = 0.f;
        #pragma unroll
        for (int g = 0; g < 2; ++g) {
            #pragma unroll
            for (int r = 0; r < 16; ++r) {
                float p = __expf(st[g][r] - m);
                st[g][r] = p;
                rs += p;
            }
        }
        rs += __shfl_xor(rs, 32);
        lsum += rs;

        // ---- write next V tile to the OTHER buffer; staging regs die here ----
        if (has_next) {
            #pragma unroll
            for (int it = 0; it < 4; ++it) {
                const int idx = tid + it * 128;
                const int r   = idx >> 3;
                const int cc  = (idx & 7) * 8;
                const ushort_t* vs = (const ushort_t*)&vr[it];
                const int chunk = r >> 3, br = r & 7;
                #pragma unroll
                for (int j = 0; j < 8; ++j) {
                    int dh = cc + j;
                    Vt[nb][dh][((chunk ^ (dh >> 3)) << 3) | br] = vs[j];
                }
            }
        }

        // ---- O^T += V^T * P^T over 4 kv-slices of 16 ----
        #pragma unroll
        for (int ks = 0; ks < 4; ++ks) {
            const int g = ks >> 1, b0 = (ks & 1) * 8;
            uint_t w0 = cvtpk(st[g][b0 + 0], st[g][b0 + 1]);
            uint_t w1 = cvtpk(st[g][b0 + 2], st[g][b0 + 3]);
            uint_t w2 = cvtpk(st[g][b0 + 4], st[g][b0 + 5]);
            uint_t w3 = cvtpk(st[g][b0 + 6], st[g][b0 + 7]);
            uint_t e0 = (uint_t)__shfl_xor((int)w0, 32);
            uint_t e1 = (uint_t)__shfl_xor((int)w1, 32);
            uint_t e2 = (uint_t)__shfl_xor((int)w2, 32);
            uint_t e3 = (uint_t)__shfl_xor((int)w3, 32);
            union { uint_t u[4]; bf16x8 v; } fr;
            fr.u[0] = hh ? e2 : w0;
            fr.u[1] = hh ? e3 : w1;
            fr.u[2] = hh ? w2 : e0;
            fr.u[3] = hh ? w3 : e1;
            const int cp0 = (((2 * ks + hh) ^ (i >> 3)) << 3);
            const int cp1 = (((2 * ks + hh) ^ (4 + (i >> 3))) << 3);
            bf16x8 va0 = *(const bf16x8*)&Vt[cb][i][cp0];
            bf16x8 va1 = *(const bf16x8*)&Vt[cb][32 + i][cp1];
            __builtin_amdgcn_s_setprio(1);
            o0 = __builtin_amdgcn_mfma_f32_32x32x16_bf16(va0, fr.v, o0, 0, 0, 0);
            o1 = __builtin_amdgcn_mfma_f32_32x32x16_bf16(va1, fr.v, o1, 0, 0, 0);
            __builtin_amdgcn_s_setprio(0);
        }

        // ---- single end-of-tile barrier (orders Vt write->read and
        //      read->overwrite across consecutive tiles) ----
        __syncthreads();
    }

    // ---- epilogue: normalize, pack bf16, store ----
    const float inv = 1.f / lsum;
    ushort_t* yrow = y + (size_t)(bT + qg) * (HEADS * DH) + h * DH;
    #pragma unroll
    for (int df = 0; df < 2; ++df) {
        const f32x16 oo = df ? o1 : o0;
        #pragma unroll
        for (int q4 = 0; q4 < 4; ++q4) {
            uint_t w0 = cvtpk(oo[q4 * 4 + 0] * inv, oo[q4 * 4 + 1] * inv);
            uint_t w1 = cvtpk(oo[q4 * 4 + 2] * inv, oo[q4 * 4 + 3] * inv);
            uint2 pk = make_uint2(w0, w1);
            *(uint2*)&yrow[df * 32 + q4 * 8 + hh * 4] = pk;
        }
    }
}

// ---------------------------------------------------------------------------
// launch
// ---------------------------------------------------------------------------
extern "C" void kernel_launch(void* const* d_in, const int* in_sizes, int n_in,
                              void* d_out, int out_size, void* d_ws, size_t ws_size,
                              hipStream_t stream) {
    const float* x     = (const float*)d_in[0];   // [B*T, 1024]
    const float* w_qkv = (const float*)d_in[1];   // [3072, 1024]
    const float* w_out = (const float*)d_in[2];   // [1024, 1024]

    const int BT = 4 * T_SEQ;                     // 8192

    char* ws = (char*)d_ws;
    ushort_t* xb   = (ushort_t*)(ws);
    ushort_t* wqb  = (ushort_t*)(ws + 16777216);
    ushort_t* wob  = (ushort_t*)(ws + 16777216 + 6291456);
    ushort_t* qkvb = (ushort_t*)(ws + 16777216 + 6291456 + 2097152);
    ushort_t* yb   = (ushort_t*)(ws + 16777216 + 6291456 + 2097152 + 50331648);

    // 1) convert inputs to bf16
    {
        int n4 = (BT * DMODEL) / 4;
        cvt_f32_bf16<<<(n4 + 255) / 256, 256, 0, stream>>>(x, xb, n4);
        n4 = (EQKV * DMODEL) / 4;
        cvt_f32_bf16<<<(n4 + 255) / 256, 256, 0, stream>>>(w_qkv, wqb, n4);
        n4 = (DMODEL * DMODEL) / 4;
        cvt_f32_bf16<<<(n4 + 255) / 256, 256, 0, stream>>>(w_out, wob, n4);
    }

    // 2) qkv = x @ w_qkv^T   (M=8192, N=3072, K=1024) -> bf16   [nwg=1536, %8==0]
    {
        dim3 grid(EQKV / BN, BT / BM);
        gemm_bt<true><<<grid, 256, 0, stream>>>(xb, wqb, (void*)qkvb, BT, EQKV, DMODEL);
    }

    // 3) flash attention -> y bf16 [BT][1024]
    {
        attn_fwd<<<2048, 128, 0, stream>>>(qkvb, yb);
    }

    // 4) out = y @ w_out^T   (M=8192, N=1024, K=1024) -> fp32   [nwg=512, %8==0]
    {
        dim3 grid(DMODEL / BN, BT / BM);
        gemm_bt<false><<<grid, 256, 0, stream>>>(yb, wob, d_out, BT, DMODEL, DMODEL);
    }
}

// Round 9
// 357.115 us; speedup vs baseline: 1.0230x; 1.0230x over previous
//
#include <hip/hip_runtime.h>
#include <hip/hip_bf16.h>

// Problem constants (CausalSelfAttention): D_MODEL=1024, H=16, Dh=64, B=4, T=2048
#define T_SEQ   2048
#define HEADS   16
#define DH      64
#define DMODEL  1024
#define EQKV    3072   // 3*H*Dh
#define BT_TOT  8192   // B*T

typedef __attribute__((ext_vector_type(8)))  __bf16 bf16x8;
typedef __attribute__((ext_vector_type(4)))  float  f32x4;
typedef __attribute__((ext_vector_type(16))) float  f32x16;
typedef unsigned short ushort_t;
typedef unsigned int   uint_t;

__device__ __forceinline__ ushort_t f2bfu(float x) {
    union { float f; uint_t u; } c; c.f = x;
    uint_t u = c.u;
    uint_t r = (u + 0x7fffu + ((u >> 16) & 1u)) >> 16;
    return (ushort_t)r;
}

// pack 2 f32 -> u32 holding 2 bf16 (lo = first arg)
__device__ __forceinline__ uint_t cvtpk(float lo, float hi) {
    uint_t r;
    asm volatile("v_cvt_pk_bf16_f32 %0, %1, %2" : "=v"(r) : "v"(lo), "v"(hi));
    return r;
}

// async global->LDS, 16B per lane; LDS dest is wave-uniform base + lane*16
__device__ __forceinline__ void gload16(const ushort_t* g, ushort_t* l) {
    __builtin_amdgcn_global_load_lds(
        (const __attribute__((address_space(1))) void*)g,
        (__attribute__((address_space(3))) void*)l,
        16, 0, 0);
}

// ---------------------------------------------------------------------------
// fp32 -> bf16 conversion (vectorized float4 in, 4 bf16 out)
// ---------------------------------------------------------------------------
__global__ void cvt_f32_bf16(const float* __restrict__ in, ushort_t* __restrict__ out, int n4) {
    int i = blockIdx.x * blockDim.x + threadIdx.x;
    if (i >= n4) return;
    const float4 v = ((const float4*)in)[i];
    ushort_t r0 = f2bfu(v.x), r1 = f2bfu(v.y), r2 = f2bfu(v.z), r3 = f2bfu(v.w);
    uint_t lo = (uint_t)r0 | ((uint_t)r1 << 16);
    uint_t hi = (uint_t)r2 | ((uint_t)r3 << 16);
    ((uint2*)out)[i] = make_uint2(lo, hi);
}

// ---------------------------------------------------------------------------
// bf16 GEMM: C = A[M][K] * Bt[N][K]^T. 128x128 tile, BK=32, 4 waves (2x2).
// global_load_lds width-16 staging into linear [128][32] LDS. XCD-chunked
// block swizzle (nwg%8==0 for both launches).
// MODE 0: fp32 output, row stride N (output projection).
// MODE 2: QKV split — cols [0,2048) -> qk buffer (bf16, row stride 2048);
//         cols [2048,3072) -> vT buffer TRANSPOSED (vT[e][token], e=col-2048).
//         Per fragment the 4 acc values are 4 consecutive tokens -> one 8B
//         store. Branch is block-uniform (col0 is 128-aligned).
// ---------------------------------------------------------------------------
#define BM 128
#define BN 128
#define BK 32

template<int MODE>
__global__ __launch_bounds__(256) void gemm_bt(const ushort_t* __restrict__ A,
                                               const ushort_t* __restrict__ Bt,
                                               void* __restrict__ Cv,
                                               ushort_t* __restrict__ VtOut,
                                               int M, int N, int K) {
    __shared__ __align__(16) ushort_t As[BM * BK];   // linear row-major 128x32
    __shared__ __align__(16) ushort_t Bs[BN * BK];

    const int tid  = threadIdx.x;
    const int gx   = gridDim.x;
    int flat = blockIdx.y * gx + blockIdx.x;
    const int nwg  = gx * gridDim.y;
    flat = (flat & 7) * (nwg >> 3) + (flat >> 3);   // XCD-chunked, bijective (nwg%8==0)
    const int bn   = flat % gx, bm = flat / gx;
    const int row0 = bm * BM, col0 = bn * BN;
    const int wid  = tid >> 6, lane = tid & 63;
    const int wr   = wid >> 1, wc = wid & 1;
    const int lr   = lane & 15, lg = lane >> 4;

    const int lrow = lane >> 2;           // 0..15 within 16-row chunk
    const int lcol = (lane & 3) * 8;      // 0,8,16,24

    f32x4 acc[4][4] = {};

    for (int k0 = 0; k0 < K; k0 += BK) {
        #pragma unroll
        for (int it = 0; it < 2; ++it) {
            const int c = wid * 2 + it;                     // 0..7
            const int r = c * 16 + lrow;
            gload16(&A [(size_t)(row0 + r) * K + k0 + lcol], &As[c * 512]);
            gload16(&Bt[(size_t)(col0 + r) * K + k0 + lcol], &Bs[c * 512]);
        }
        __syncthreads();

        bf16x8 bfr[4];
        #pragma unroll
        for (int n = 0; n < 4; ++n)
            bfr[n] = *(const bf16x8*)&Bs[(wc * 64 + n * 16 + lr) * BK + lg * 8];
        #pragma unroll
        for (int m = 0; m < 4; ++m) {
            bf16x8 a = *(const bf16x8*)&As[(wr * 64 + m * 16 + lr) * BK + lg * 8];
            #pragma unroll
            for (int n = 0; n < 4; ++n)
                acc[m][n] = __builtin_amdgcn_mfma_f32_16x16x32_bf16(a, bfr[n], acc[m][n], 0, 0, 0);
        }
        __syncthreads();
    }

    if (MODE == 2 && col0 >= 2048) {
        // V block: transposed 8B stores (4 consecutive tokens per fragment)
        #pragma unroll
        for (int m = 0; m < 4; ++m) {
            int rowb = row0 + wr * 64 + m * 16 + lg * 4;
            #pragma unroll
            for (int n = 0; n < 4; ++n) {
                int e = col0 - 2048 + wc * 64 + n * 16 + lr;
                uint_t lo = (uint_t)f2bfu(acc[m][n][0]) | ((uint_t)f2bfu(acc[m][n][1]) << 16);
                uint_t hi = (uint_t)f2bfu(acc[m][n][2]) | ((uint_t)f2bfu(acc[m][n][3]) << 16);
                *(uint2*)&VtOut[(size_t)e * BT_TOT + rowb] = make_uint2(lo, hi);
            }
        }
    } else {
        const int ostride = (MODE == 2) ? 2048 : N;
        #pragma unroll
        for (int m = 0; m < 4; ++m) {
            int rowb = row0 + wr * 64 + m * 16 + lg * 4;
            #pragma unroll
            for (int n = 0; n < 4; ++n) {
                int col = col0 + wc * 64 + n * 16 + lr;
                #pragma unroll
                for (int i = 0; i < 4; ++i) {
                    if (MODE == 2)
                        ((ushort_t*)Cv)[(size_t)(rowb + i) * ostride + col] = f2bfu(acc[m][n][i]);
                    else
                        ((float*)Cv)[(size_t)(rowb + i) * ostride + col] = acc[m][n][i];
                }
            }
        }
    }
}

// ---------------------------------------------------------------------------
// Causal flash attention, swapped-QK^T 32x32x16 structure.
// One block = 64 q rows of one (b,h); 2 waves x 32 q rows. KV tiles of 64.
// CU remap (proven round 6): each CU hosts one (b,h), balanced bx set.
// Q/K read from qk buffer (stride 2048); V read from vT[e][token] — already
// transposed by the GEMM, so staging is plain b128 register->LDS (the
// conflict-free pattern) and PV fragments are contiguous row reads.
// Ks single-buffered (read only in QK^T phase), Vl double-buffered:
// LDS 27.6KB -> 5 blocks/CU. Two barriers/tile. Defer-max; setprio.
// ---------------------------------------------------------------------------
__global__ __launch_bounds__(128, 3) void attn_fwd(const ushort_t* __restrict__ qk,
                                                   const ushort_t* __restrict__ vt,
                                                   ushort_t* __restrict__ y) {
    const int flat = blockIdx.x;
    const int xcd  = flat & 7;
    const int s    = flat >> 3;              // 0..255
    const int bh   = xcd * 8 + (s & 7);      // 0..63  (b*16+h)
    const int bx   = 31 - (s >> 3);          // heavy-first within CU
    const int b    = bh >> 4, h = bh & 15;
    const int tid  = threadIdx.x, lane = tid & 63;
    const int wid  = tid >> 6;
    const int i    = lane & 31;              // q column within warp tile
    const int hh   = lane >> 5;              // k-half selector
    const int bT   = b * T_SEQ;

    __shared__ __align__(16) ushort_t Ks[64][72];       // [kv][dh] single-buffered
    __shared__ __align__(16) ushort_t Vl[2][64][72];    // [buf][dh][kv] (V^T tile)

    const int q0 = bx * 64 + wid * 32;
    const int qg = q0 + i;

    // Q B-fragments: col=q (lane&31), k=dh = kd*16 + hh*8 + j ; pre-scaled 1/8
    bf16x8 qf[4];
    {
        const ushort_t* qrow = qk + (size_t)(bT + qg) * 2048 + h * DH;
        #pragma unroll
        for (int kd = 0; kd < 4; ++kd) {
            bf16x8 q = *(const bf16x8*)&qrow[kd * 16 + hh * 8];
            #pragma unroll
            for (int j = 0; j < 8; ++j)
                ((ushort_t*)&q)[j] = f2bfu(__bfloat162float(
                    *(const __hip_bfloat16*)&((ushort_t*)&q)[j]) * 0.125f);
            qf[kd] = q;
        }
    }

    // staging coords: idx = tid + it*128 in [0,512): r = idx>>3, cc = (idx&7)*8
    float m = -1e30f, lsum = 0.f;
    f32x16 o0 = {}, o1 = {};

    const int nt = bx + 1;                   // kv tiles 0..bx

    // ---- stage tile 0: K rows + V^T rows ----
    #pragma unroll
    for (int it = 0; it < 4; ++it) {
        const int idx = tid + it * 128;
        const int r   = idx >> 3;            // K: kv row / V: dh row
        const int cc  = (idx & 7) * 8;
        *(uint4*)&Ks[r][cc]    = *(const uint4*)&qk[(size_t)(bT + r) * 2048 + 1024 + h * DH + cc];
        *(uint4*)&Vl[0][r][cc] = *(const uint4*)&vt[(size_t)(h * DH + r) * BT_TOT + bT + cc];
    }
    __syncthreads();

    for (int t = 0; t < nt; ++t) {
        const int cb = t & 1, nb = cb ^ 1;
        const bool has_next = (t + 1 < nt);
        const int kmin = t * 64;

        // ---- (a) issue next tile's global loads ----
        uint4 kr[4], vr[4];
        if (has_next) {
            #pragma unroll
            for (int it = 0; it < 4; ++it) {
                const int idx = tid + it * 128;
                const int r   = idx >> 3;
                const int cc  = (idx & 7) * 8;
                kr[it] = *(const uint4*)&qk[(size_t)(bT + kmin + 64 + r) * 2048 + 1024 + h * DH + cc];
                vr[it] = *(const uint4*)&vt[(size_t)(h * DH + r) * BT_TOT + bT + kmin + 64 + cc];
            }
        }

        // ---- (b) S^T = K * Q^T ----
        f32x16 st[2] = {};
        __builtin_amdgcn_s_setprio(1);
        #pragma unroll
        for (int kd = 0; kd < 4; ++kd) {
            bf16x8 ka0 = *(const bf16x8*)&Ks[i][kd * 16 + hh * 8];
            bf16x8 ka1 = *(const bf16x8*)&Ks[32 + i][kd * 16 + hh * 8];
            st[0] = __builtin_amdgcn_mfma_f32_32x32x16_bf16(ka0, qf[kd], st[0], 0, 0, 0);
            st[1] = __builtin_amdgcn_mfma_f32_32x32x16_bf16(ka1, qf[kd], st[1], 0, 0, 0);
        }
        __builtin_amdgcn_s_setprio(0);

        // ---- (c) barrier: all waves done reading Ks ----
        __syncthreads();

        // ---- (d) write next K and V^T tiles to LDS; staging regs die ----
        if (has_next) {
            #pragma unroll
            for (int it = 0; it < 4; ++it) {
                const int idx = tid + it * 128;
                const int r   = idx >> 3;
                const int cc  = (idx & 7) * 8;
                *(uint4*)&Ks[r][cc]     = kr[it];
                *(uint4*)&Vl[nb][r][cc] = vr[it];
            }
        }

        // ---- (e) mask + row max + online softmax (defer-max) ----
        const bool needmask = (kmin + 63) > q0;
        float pm = -1e30f;
        #pragma unroll
        for (int g = 0; g < 2; ++g) {
            #pragma unroll
            for (int r = 0; r < 16; ++r) {
                float v = st[g][r];
                if (needmask) {
                    int kv = kmin + g * 32 + (r & 3) + 8 * (r >> 2) + 4 * hh;
                    v = (kv <= qg) ? v : -1e30f;
                    st[g][r] = v;
                }
                pm = fmaxf(pm, v);
            }
        }
        pm = fmaxf(pm, __shfl_xor(pm, 32));

        if (!__all(pm - m <= 8.f)) {
            const float mnew = fmaxf(m, pm);
            const float corr = __expf(m - mnew);
            m = mnew;
            lsum *= corr;
            #pragma unroll
            for (int r = 0; r < 16; ++r) { o0[r] *= corr; o1[r] *= corr; }
        }
        float rs = 0.f;
        #pragma unroll
        for (int g = 0; g < 2; ++g) {
            #pragma unroll
            for (int r = 0; r < 16; ++r) {
                float p = __expf(st[g][r] - m);
                st[g][r] = p;
                rs += p;
            }
        }
        rs += __shfl_xor(rs, 32);
        lsum += rs;

        // ---- (f) O^T += V^T * P^T over 4 kv-slices of 16 ----
        #pragma unroll
        for (int ks = 0; ks < 4; ++ks) {
            const int g = ks >> 1, b0 = (ks & 1) * 8;
            uint_t w0 = cvtpk(st[g][b0 + 0], st[g][b0 + 1]);
            uint_t w1 = cvtpk(st[g][b0 + 2], st[g][b0 + 3]);
            uint_t w2 = cvtpk(st[g][b0 + 4], st[g][b0 + 5]);
            uint_t w3 = cvtpk(st[g][b0 + 6], st[g][b0 + 7]);
            uint_t e0 = (uint_t)__shfl_xor((int)w0, 32);
            uint_t e1 = (uint_t)__shfl_xor((int)w1, 32);
            uint_t e2 = (uint_t)__shfl_xor((int)w2, 32);
            uint_t e3 = (uint_t)__shfl_xor((int)w3, 32);
            union { uint_t u[4]; bf16x8 v; } fr;
            fr.u[0] = hh ? e2 : w0;
            fr.u[1] = hh ? e3 : w1;
            fr.u[2] = hh ? w2 : e0;
            fr.u[3] = hh ? w3 : e1;
            bf16x8 va0 = *(const bf16x8*)&Vl[cb][i][ks * 16 + hh * 8];
            bf16x8 va1 = *(const bf16x8*)&Vl[cb][32 + i][ks * 16 + hh * 8];
            __builtin_amdgcn_s_setprio(1);
            o0 = __builtin_amdgcn_mfma_f32_32x32x16_bf16(va0, fr.v, o0, 0, 0, 0);
            o1 = __builtin_amdgcn_mfma_f32_32x32x16_bf16(va1, fr.v, o1, 0, 0, 0);
            __builtin_amdgcn_s_setprio(0);
        }

        // ---- (g) barrier: LDS writes visible; reads done before overwrite ----
        __syncthreads();
    }

    // ---- epilogue: normalize, pack bf16, store ----
    const float inv = 1.f / lsum;
    ushort_t* yrow = y + (size_t)(bT + qg) * (HEADS * DH) + h * DH;
    #pragma unroll
    for (int df = 0; df < 2; ++df) {
        const f32x16 oo = df ? o1 : o0;
        #pragma unroll
        for (int q4 = 0; q4 < 4; ++q4) {
            uint_t w0 = cvtpk(oo[q4 * 4 + 0] * inv, oo[q4 * 4 + 1] * inv);
            uint_t w1 = cvtpk(oo[q4 * 4 + 2] * inv, oo[q4 * 4 + 3] * inv);
            uint2 pk = make_uint2(w0, w1);
            *(uint2*)&yrow[df * 32 + q4 * 8 + hh * 4] = pk;
        }
    }
}

// ---------------------------------------------------------------------------
// launch
// ---------------------------------------------------------------------------
extern "C" void kernel_launch(void* const* d_in, const int* in_sizes, int n_in,
                              void* d_out, int out_size, void* d_ws, size_t ws_size,
                              hipStream_t stream) {
    const float* x     = (const float*)d_in[0];   // [B*T, 1024]
    const float* w_qkv = (const float*)d_in[1];   // [3072, 1024]
    const float* w_out = (const float*)d_in[2];   // [1024, 1024]

    const int BT = BT_TOT;                        // 8192

    char* ws = (char*)d_ws;
    ushort_t* xb  = (ushort_t*)(ws);                       // 16.78 MB
    ushort_t* wqb = (ushort_t*)(ws + 16777216);            //  6.29 MB
    ushort_t* wob = (ushort_t*)(ws + 23068672);            //  2.10 MB
    ushort_t* qkb = (ushort_t*)(ws + 25165824);            // 33.55 MB [token][2048]
    ushort_t* vtb = (ushort_t*)(ws + 58720256);            // 16.78 MB [e][token]
    ushort_t* yb  = (ushort_t*)(ws + 75497472);            // 16.78 MB
    // total 92.27 MB (same as previous rounds)

    // 1) convert inputs to bf16
    {
        int n4 = (BT * DMODEL) / 4;
        cvt_f32_bf16<<<(n4 + 255) / 256, 256, 0, stream>>>(x, xb, n4);
        n4 = (EQKV * DMODEL) / 4;
        cvt_f32_bf16<<<(n4 + 255) / 256, 256, 0, stream>>>(w_qkv, wqb, n4);
        n4 = (DMODEL * DMODEL) / 4;
        cvt_f32_bf16<<<(n4 + 255) / 256, 256, 0, stream>>>(w_out, wob, n4);
    }

    // 2) qkv = x @ w_qkv^T -> Q,K to qkb (stride 2048); V transposed to vtb
    {
        dim3 grid(EQKV / BN, BT / BM);   // nwg = 1536, %8 == 0
        gemm_bt<2><<<grid, 256, 0, stream>>>(xb, wqb, (void*)qkb, vtb, BT, EQKV, DMODEL);
    }

    // 3) flash attention -> y bf16 [BT][1024]
    {
        attn_fwd<<<2048, 128, 0, stream>>>(qkb, vtb, yb);
    }

    // 4) out = y @ w_out^T   (M=8192, N=1024, K=1024) -> fp32
    {
        dim3 grid(DMODEL / BN, BT / BM); // nwg = 512, %8 == 0
        gemm_bt<0><<<grid, 256, 0, stream>>>(yb, wob, d_out, nullptr, BT, DMODEL, DMODEL);
    }
}

// Round 10
// 284.276 us; speedup vs baseline: 1.2851x; 1.2562x over previous
//
#include <hip/hip_runtime.h>
#include <hip/hip_bf16.h>

// Problem constants (CausalSelfAttention): D_MODEL=1024, H=16, Dh=64, B=4, T=2048
#define T_SEQ   2048
#define HEADS   16
#define DH      64
#define DMODEL  1024
#define EQKV    3072   // 3*H*Dh
#define BT_TOT  8192   // B*T

typedef __attribute__((ext_vector_type(8)))  __bf16 bf16x8;
typedef __attribute__((ext_vector_type(4)))  float  f32x4;
typedef __attribute__((ext_vector_type(16))) float  f32x16;
typedef unsigned short ushort_t;
typedef unsigned int   uint_t;

__device__ __forceinline__ ushort_t f2bfu(float x) {
    union { float f; uint_t u; } c; c.f = x;
    uint_t u = c.u;
    uint_t r = (u + 0x7fffu + ((u >> 16) & 1u)) >> 16;
    return (ushort_t)r;
}

// pack 2 f32 -> u32 holding 2 bf16 (lo = first arg)
__device__ __forceinline__ uint_t cvtpk(float lo, float hi) {
    uint_t r;
    asm volatile("v_cvt_pk_bf16_f32 %0, %1, %2" : "=v"(r) : "v"(lo), "v"(hi));
    return r;
}

// async global->LDS, 16B per lane; LDS dest is wave-uniform base + lane*16
__device__ __forceinline__ void gload16(const ushort_t* g, ushort_t* l) {
    __builtin_amdgcn_global_load_lds(
        (const __attribute__((address_space(1))) void*)g,
        (__attribute__((address_space(3))) void*)l,
        16, 0, 0);
}

// ---------------------------------------------------------------------------
// fp32 -> bf16 conversion (vectorized float4 in, 4 bf16 out)
// ---------------------------------------------------------------------------
__global__ void cvt_f32_bf16(const float* __restrict__ in, ushort_t* __restrict__ out, int n4) {
    int i = blockIdx.x * blockDim.x + threadIdx.x;
    if (i >= n4) return;
    const float4 v = ((const float4*)in)[i];
    ushort_t r0 = f2bfu(v.x), r1 = f2bfu(v.y), r2 = f2bfu(v.z), r3 = f2bfu(v.w);
    uint_t lo = (uint_t)r0 | ((uint_t)r1 << 16);
    uint_t hi = (uint_t)r2 | ((uint_t)r3 << 16);
    ((uint2*)out)[i] = make_uint2(lo, hi);
}

// ---------------------------------------------------------------------------
// bf16 GEMM: C = A[M][K] * Bt[N][K]^T. 128x128 tile, BK=32, 4 waves (2x2).
// global_load_lds width-16 staging into linear [128][32] LDS. XCD-chunked
// block swizzle (nwg%8==0 for both launches).
// MODE 0: fp32 output, row stride N (output projection).
// MODE 2: QKV split — cols [0,2048) -> qk buffer (bf16, row stride 2048);
//         cols [2048,3072) -> vT buffer TRANSPOSED (vT[e][token]).
// ---------------------------------------------------------------------------
#define BM 128
#define BN 128
#define BK 32

template<int MODE>
__global__ __launch_bounds__(256) void gemm_bt(const ushort_t* __restrict__ A,
                                               const ushort_t* __restrict__ Bt,
                                               void* __restrict__ Cv,
                                               ushort_t* __restrict__ VtOut,
                                               int M, int N, int K) {
    __shared__ __align__(16) ushort_t As[BM * BK];   // linear row-major 128x32
    __shared__ __align__(16) ushort_t Bs[BN * BK];

    const int tid  = threadIdx.x;
    const int gx   = gridDim.x;
    int flat = blockIdx.y * gx + blockIdx.x;
    const int nwg  = gx * gridDim.y;
    flat = (flat & 7) * (nwg >> 3) + (flat >> 3);   // XCD-chunked, bijective (nwg%8==0)
    const int bn   = flat % gx, bm = flat / gx;
    const int row0 = bm * BM, col0 = bn * BN;
    const int wid  = tid >> 6, lane = tid & 63;
    const int wr   = wid >> 1, wc = wid & 1;
    const int lr   = lane & 15, lg = lane >> 4;

    const int lrow = lane >> 2;           // 0..15 within 16-row chunk
    const int lcol = (lane & 3) * 8;      // 0,8,16,24

    f32x4 acc[4][4] = {};

    for (int k0 = 0; k0 < K; k0 += BK) {
        #pragma unroll
        for (int it = 0; it < 2; ++it) {
            const int c = wid * 2 + it;                     // 0..7
            const int r = c * 16 + lrow;
            gload16(&A [(size_t)(row0 + r) * K + k0 + lcol], &As[c * 512]);
            gload16(&Bt[(size_t)(col0 + r) * K + k0 + lcol], &Bs[c * 512]);
        }
        __syncthreads();

        bf16x8 bfr[4];
        #pragma unroll
        for (int n = 0; n < 4; ++n)
            bfr[n] = *(const bf16x8*)&Bs[(wc * 64 + n * 16 + lr) * BK + lg * 8];
        #pragma unroll
        for (int m = 0; m < 4; ++m) {
            bf16x8 a = *(const bf16x8*)&As[(wr * 64 + m * 16 + lr) * BK + lg * 8];
            #pragma unroll
            for (int n = 0; n < 4; ++n)
                acc[m][n] = __builtin_amdgcn_mfma_f32_16x16x32_bf16(a, bfr[n], acc[m][n], 0, 0, 0);
        }
        __syncthreads();
    }

    if (MODE == 2 && col0 >= 2048) {
        // V block: transposed 8B stores (4 consecutive tokens per fragment)
        #pragma unroll
        for (int m = 0; m < 4; ++m) {
            int rowb = row0 + wr * 64 + m * 16 + lg * 4;
            #pragma unroll
            for (int n = 0; n < 4; ++n) {
                int e = col0 - 2048 + wc * 64 + n * 16 + lr;
                uint_t lo = (uint_t)f2bfu(acc[m][n][0]) | ((uint_t)f2bfu(acc[m][n][1]) << 16);
                uint_t hi = (uint_t)f2bfu(acc[m][n][2]) | ((uint_t)f2bfu(acc[m][n][3]) << 16);
                *(uint2*)&VtOut[(size_t)e * BT_TOT + rowb] = make_uint2(lo, hi);
            }
        }
    } else {
        const int ostride = (MODE == 2) ? 2048 : N;
        #pragma unroll
        for (int m = 0; m < 4; ++m) {
            int rowb = row0 + wr * 64 + m * 16 + lg * 4;
            #pragma unroll
            for (int n = 0; n < 4; ++n) {
                int col = col0 + wc * 64 + n * 16 + lr;
                #pragma unroll
                for (int i = 0; i < 4; ++i) {
                    if (MODE == 2)
                        ((ushort_t*)Cv)[(size_t)(rowb + i) * ostride + col] = f2bfu(acc[m][n][i]);
                    else
                        ((float*)Cv)[(size_t)(rowb + i) * ostride + col] = acc[m][n][i];
                }
            }
        }
    }
}

// ---------------------------------------------------------------------------
// Causal flash attention, swapped-QK^T 32x32x16 structure.
// One block = 64 q rows of one (b,h); 2 waves x 32 q rows. KV tiles of 64.
// CU remap (proven round 6): each CU hosts one (b,h), balanced bx set.
// ROUND 10: NO register staging — K and V^T tiles stream via
// global_load_lds into linear [64][64] double buffers (zero VGPR cost, no
// spill). Source-side XOR swizzle ((l&7)^(l>>3), rule #21 both-sides) so
// b128 reads are 2-way (free). Issue loads -> compute tile -> one barrier
// (its vmcnt(0) drain lands after the full compute phase = latency hidden).
// LDS 32KB -> 5 blocks/CU. Defer-max; setprio.
// ---------------------------------------------------------------------------
__global__ __launch_bounds__(128, 2) void attn_fwd(const ushort_t* __restrict__ qk,
                                                   const ushort_t* __restrict__ vt,
                                                   ushort_t* __restrict__ y) {
    const int flat = blockIdx.x;
    const int xcd  = flat & 7;
    const int s    = flat >> 3;              // 0..255
    const int bh   = xcd * 8 + (s & 7);      // 0..63  (b*16+h)
    const int bx   = 31 - (s >> 3);          // heavy-first within CU
    const int b    = bh >> 4, h = bh & 15;
    const int tid  = threadIdx.x, lane = tid & 63;
    const int w    = tid >> 6;
    const int i    = lane & 31;              // q column within warp tile
    const int hh   = lane >> 5;              // k-half selector
    const int bT   = b * T_SEQ;

    // linear [64 rows][64 cols] bf16, data chunk-XOR-swizzled: lds[r][c^(r&7)]
    __shared__ __align__(16) ushort_t KsL[2][64 * 64];
    __shared__ __align__(16) ushort_t VlL[2][64 * 64];

    const int q0 = bx * 64 + w * 32;
    const int qg = q0 + i;

    // Q B-fragments: col=q (lane&31), k=dh = kd*16 + hh*8 + j ; pre-scaled 1/8
    bf16x8 qf[4];
    {
        const ushort_t* qrow = qk + (size_t)(bT + qg) * 2048 + h * DH;
        #pragma unroll
        for (int kd = 0; kd < 4; ++kd) {
            bf16x8 q = *(const bf16x8*)&qrow[kd * 16 + hh * 8];
            #pragma unroll
            for (int j = 0; j < 8; ++j)
                ((ushort_t*)&q)[j] = f2bfu(__bfloat162float(
                    *(const __hip_bfloat16*)&((ushort_t*)&q)[j]) * 0.125f);
            qf[kd] = q;
        }
    }

    // staging geometry (per lane, constant): row-in-group = l>>3, source
    // chunk = (l&7)^(l>>3) (inverse swizzle). Wave w covers rows w*32+it*8..+7.
    const int lr8    = lane >> 3;                       // 0..7
    const int schunk = ((lane & 7) ^ lr8) * 8;          // ushort offset in row
    const int rbase  = w * 32;                          // wave's row base

    float m = -1e30f, lsum = 0.f;
    f32x16 o0 = {}, o1 = {};

    const int nt = bx + 1;                   // kv tiles 0..bx

    // ---- prologue: stage tile 0 into buffer 0 ----
    #pragma unroll
    for (int it = 0; it < 4; ++it) {
        const int rg = rbase + it * 8;                 // row group base
        const int r  = rg + lr8;                       // this lane's row
        gload16(&qk[(size_t)(bT + r) * 2048 + 1024 + h * DH + schunk], &KsL[0][rg * 64]);
        gload16(&vt[(size_t)(h * DH + r) * BT_TOT + bT + schunk],      &VlL[0][rg * 64]);
    }
    __syncthreads();

    for (int t = 0; t < nt; ++t) {
        const int cb = t & 1, nb = cb ^ 1;
        const bool has_next = (t + 1 < nt);
        const int kmin = t * 64;

        // ---- (a) issue next tile's async loads into the other buffer ----
        if (has_next) {
            const int kt = kmin + 64;
            #pragma unroll
            for (int it = 0; it < 4; ++it) {
                const int rg = rbase + it * 8;
                const int r  = rg + lr8;
                gload16(&qk[(size_t)(bT + kt + r) * 2048 + 1024 + h * DH + schunk], &KsL[nb][rg * 64]);
                gload16(&vt[(size_t)(h * DH + r) * BT_TOT + bT + kt + schunk],      &VlL[nb][rg * 64]);
            }
        }

        // ---- (b) S^T = K * Q^T (reads swizzled: chunk cq ^ (row&7)) ----
        f32x16 st[2] = {};
        __builtin_amdgcn_s_setprio(1);
        #pragma unroll
        for (int kd = 0; kd < 4; ++kd) {
            const int cq = kd * 2 + hh;
            bf16x8 ka0 = *(const bf16x8*)&KsL[cb][i * 64        + ((cq ^ (i & 7)) * 8)];
            bf16x8 ka1 = *(const bf16x8*)&KsL[cb][(32 + i) * 64 + ((cq ^ (i & 7)) * 8)];
            st[0] = __builtin_amdgcn_mfma_f32_32x32x16_bf16(ka0, qf[kd], st[0], 0, 0, 0);
            st[1] = __builtin_amdgcn_mfma_f32_32x32x16_bf16(ka1, qf[kd], st[1], 0, 0, 0);
        }
        __builtin_amdgcn_s_setprio(0);

        // ---- (c) mask + row max + online softmax (defer-max) ----
        const bool needmask = (kmin + 63) > q0;
        float pm = -1e30f;
        #pragma unroll
        for (int g = 0; g < 2; ++g) {
            #pragma unroll
            for (int r = 0; r < 16; ++r) {
                float v = st[g][r];
                if (needmask) {
                    int kv = kmin + g * 32 + (r & 3) + 8 * (r >> 2) + 4 * hh;
                    v = (kv <= qg) ? v : -1e30f;
                    st[g][r] = v;
                }
                pm = fmaxf(pm, v);
            }
        }
        pm = fmaxf(pm, __shfl_xor(pm, 32));

        if (!__all(pm - m <= 8.f)) {
            const float mnew = fmaxf(m, pm);
            const float corr = __expf(m - mnew);
            m = mnew;
            lsum *= corr;
            #pragma unroll
            for (int r = 0; r < 16; ++r) { o0[r] *= corr; o1[r] *= corr; }
        }
        float rs = 0.f;
        #pragma unroll
        for (int g = 0; g < 2; ++g) {
            #pragma unroll
            for (int r = 0; r < 16; ++r) {
                float p = __expf(st[g][r] - m);
                st[g][r] = p;
                rs += p;
            }
        }
        rs += __shfl_xor(rs, 32);
        lsum += rs;

        // ---- (d) O^T += V^T * P^T over 4 kv-slices of 16 ----
        #pragma unroll
        for (int ks = 0; ks < 4; ++ks) {
            const int g = ks >> 1, b0 = (ks & 1) * 8;
            uint_t w0 = cvtpk(st[g][b0 + 0], st[g][b0 + 1]);
            uint_t w1 = cvtpk(st[g][b0 + 2], st[g][b0 + 3]);
            uint_t w2 = cvtpk(st[g][b0 + 4], st[g][b0 + 5]);
            uint_t w3 = cvtpk(st[g][b0 + 6], st[g][b0 + 7]);
            uint_t e0 = (uint_t)__shfl_xor((int)w0, 32);
            uint_t e1 = (uint_t)__shfl_xor((int)w1, 32);
            uint_t e2 = (uint_t)__shfl_xor((int)w2, 32);
            uint_t e3 = (uint_t)__shfl_xor((int)w3, 32);
            union { uint_t u[4]; bf16x8 v; } fr;
            fr.u[0] = hh ? e2 : w0;
            fr.u[1] = hh ? e3 : w1;
            fr.u[2] = hh ? w2 : e0;
            fr.u[3] = hh ? w3 : e1;
            const int ct = ks * 2 + hh;
            bf16x8 va0 = *(const bf16x8*)&VlL[cb][i * 64        + ((ct ^ (i & 7)) * 8)];
            bf16x8 va1 = *(const bf16x8*)&VlL[cb][(32 + i) * 64 + ((ct ^ (i & 7)) * 8)];
            __builtin_amdgcn_s_setprio(1);
            o0 = __builtin_amdgcn_mfma_f32_32x32x16_bf16(va0, fr.v, o0, 0, 0, 0);
            o1 = __builtin_amdgcn_mfma_f32_32x32x16_bf16(va1, fr.v, o1, 0, 0, 0);
            __builtin_amdgcn_s_setprio(0);
        }

        // ---- (e) one barrier: drains async loads (vmcnt) after a full
        //      compute phase; orders reads-done before next overwrite ----
        __syncthreads();
    }

    // ---- epilogue: normalize, pack bf16, store ----
    const float inv = 1.f / lsum;
    ushort_t* yrow = y + (size_t)(bT + qg) * (HEADS * DH) + h * DH;
    #pragma unroll
    for (int df = 0; df < 2; ++df) {
        const f32x16 oo = df ? o1 : o0;
        #pragma unroll
        for (int q4 = 0; q4 < 4; ++q4) {
            uint_t w0 = cvtpk(oo[q4 * 4 + 0] * inv, oo[q4 * 4 + 1] * inv);
            uint_t w1 = cvtpk(oo[q4 * 4 + 2] * inv, oo[q4 * 4 + 3] * inv);
            uint2 pk = make_uint2(w0, w1);
            *(uint2*)&yrow[df * 32 + q4 * 8 + hh * 4] = pk;
        }
    }
}

// ---------------------------------------------------------------------------
// launch
// ---------------------------------------------------------------------------
extern "C" void kernel_launch(void* const* d_in, const int* in_sizes, int n_in,
                              void* d_out, int out_size, void* d_ws, size_t ws_size,
                              hipStream_t stream) {
    const float* x     = (const float*)d_in[0];   // [B*T, 1024]
    const float* w_qkv = (const float*)d_in[1];   // [3072, 1024]
    const float* w_out = (const float*)d_in[2];   // [1024, 1024]

    const int BT = BT_TOT;                        // 8192

    char* ws = (char*)d_ws;
    ushort_t* xb  = (ushort_t*)(ws);                       // 16.78 MB
    ushort_t* wqb = (ushort_t*)(ws + 16777216);            //  6.29 MB
    ushort_t* wob = (ushort_t*)(ws + 23068672);            //  2.10 MB
    ushort_t* qkb = (ushort_t*)(ws + 25165824);            // 33.55 MB [token][2048]
    ushort_t* vtb = (ushort_t*)(ws + 58720256);            // 16.78 MB [e][token]
    ushort_t* yb  = (ushort_t*)(ws + 75497472);            // 16.78 MB

    // 1) convert inputs to bf16
    {
        int n4 = (BT * DMODEL) / 4;
        cvt_f32_bf16<<<(n4 + 255) / 256, 256, 0, stream>>>(x, xb, n4);
        n4 = (EQKV * DMODEL) / 4;
        cvt_f32_bf16<<<(n4 + 255) / 256, 256, 0, stream>>>(w_qkv, wqb, n4);
        n4 = (DMODEL * DMODEL) / 4;
        cvt_f32_bf16<<<(n4 + 255) / 256, 256, 0, stream>>>(w_out, wob, n4);
    }

    // 2) qkv = x @ w_qkv^T -> Q,K to qkb (stride 2048); V transposed to vtb
    {
        dim3 grid(EQKV / BN, BT / BM);   // nwg = 1536, %8 == 0
        gemm_bt<2><<<grid, 256, 0, stream>>>(xb, wqb, (void*)qkb, vtb, BT, EQKV, DMODEL);
    }

    // 3) flash attention -> y bf16 [BT][1024]
    {
        attn_fwd<<<2048, 128, 0, stream>>>(qkb, vtb, yb);
    }

    // 4) out = y @ w_out^T   (M=8192, N=1024, K=1024) -> fp32
    {
        dim3 grid(DMODEL / BN, BT / BM); // nwg = 512, %8 == 0
        gemm_bt<0><<<grid, 256, 0, stream>>>(yb, wob, d_out, nullptr, BT, DMODEL, DMODEL);
    }
}

// Round 11
// 282.639 us; speedup vs baseline: 1.2925x; 1.0058x over previous
//
#include <hip/hip_runtime.h>
#include <hip/hip_bf16.h>

// Problem constants (CausalSelfAttention): D_MODEL=1024, H=16, Dh=64, B=4, T=2048
#define T_SEQ   2048
#define HEADS   16
#define DH      64
#define DMODEL  1024
#define EQKV    3072   // 3*H*Dh
#define BT_TOT  8192   // B*T

typedef __attribute__((ext_vector_type(8)))  __bf16 bf16x8;
typedef __attribute__((ext_vector_type(4)))  float  f32x4;
typedef __attribute__((ext_vector_type(16))) float  f32x16;
typedef unsigned int __attribute__((ext_vector_type(2))) uint2v;
typedef unsigned short ushort_t;
typedef unsigned int   uint_t;

__device__ __forceinline__ ushort_t f2bfu(float x) {
    union { float f; uint_t u; } c; c.f = x;
    uint_t u = c.u;
    uint_t r = (u + 0x7fffu + ((u >> 16) & 1u)) >> 16;
    return (ushort_t)r;
}

// pack 2 f32 -> u32 holding 2 bf16 (lo = first arg)
__device__ __forceinline__ uint_t cvtpk(float lo, float hi) {
    uint_t r;
    asm volatile("v_cvt_pk_bf16_f32 %0, %1, %2" : "=v"(r) : "v"(lo), "v"(hi));
    return r;
}

// T12: half-wave exchange via the documented builtin (clean SSA, unlike
// round-5's aliased raw asm). After call:
//   a[l] = l<32 ? a_old[l]    : b_old[l-32]
//   b[l] = l<32 ? a_old[l+32] : b_old[l]
__device__ __forceinline__ void plswap(uint_t& a, uint_t& b) {
    uint2v r = __builtin_amdgcn_permlane32_swap(a, b, false, false);
    a = r[0]; b = r[1];
}

__device__ __forceinline__ float halfmax(float x) {
    uint_t a = __float_as_uint(x), b = a;
    plswap(a, b);
    return fmaxf(__uint_as_float(a), __uint_as_float(b));
}

__device__ __forceinline__ float halfadd(float x) {
    uint_t a = __float_as_uint(x), b = a;
    plswap(a, b);
    return __uint_as_float(a) + __uint_as_float(b);
}

// v_exp_f32 computes 2^x natively (exp2-domain softmax)
__device__ __forceinline__ float exp2v(float x) {
    float r;
    asm("v_exp_f32 %0, %1" : "=v"(r) : "v"(x));
    return r;
}

// async global->LDS, 16B per lane; LDS dest is wave-uniform base + lane*16
__device__ __forceinline__ void gload16(const ushort_t* g, ushort_t* l) {
    __builtin_amdgcn_global_load_lds(
        (const __attribute__((address_space(1))) void*)g,
        (__attribute__((address_space(3))) void*)l,
        16, 0, 0);
}

// ---------------------------------------------------------------------------
// fp32 -> bf16 conversion (vectorized float4 in, 4 bf16 out)
// ---------------------------------------------------------------------------
__global__ void cvt_f32_bf16(const float* __restrict__ in, ushort_t* __restrict__ out, int n4) {
    int i = blockIdx.x * blockDim.x + threadIdx.x;
    if (i >= n4) return;
    const float4 v = ((const float4*)in)[i];
    ushort_t r0 = f2bfu(v.x), r1 = f2bfu(v.y), r2 = f2bfu(v.z), r3 = f2bfu(v.w);
    uint_t lo = (uint_t)r0 | ((uint_t)r1 << 16);
    uint_t hi = (uint_t)r2 | ((uint_t)r3 << 16);
    ((uint2*)out)[i] = make_uint2(lo, hi);
}

// ---------------------------------------------------------------------------
// bf16 GEMM: C = A[M][K] * Bt[N][K]^T. 128x128 tile, BK=32, 4 waves (2x2).
// global_load_lds width-16 staging into linear [128][32] LDS. XCD-chunked
// block swizzle (nwg%8==0 for both launches).
// MODE 0: fp32 output, row stride N (output projection).
// MODE 2: QKV split — cols [0,2048) -> qk buffer (bf16, row stride 2048);
//         cols [2048,3072) -> vT buffer TRANSPOSED (vT[e][token]).
// ---------------------------------------------------------------------------
#define BM 128
#define BN 128
#define BK 32

template<int MODE>
__global__ __launch_bounds__(256) void gemm_bt(const ushort_t* __restrict__ A,
                                               const ushort_t* __restrict__ Bt,
                                               void* __restrict__ Cv,
                                               ushort_t* __restrict__ VtOut,
                                               int M, int N, int K) {
    __shared__ __align__(16) ushort_t As[BM * BK];   // linear row-major 128x32
    __shared__ __align__(16) ushort_t Bs[BN * BK];

    const int tid  = threadIdx.x;
    const int gx   = gridDim.x;
    int flat = blockIdx.y * gx + blockIdx.x;
    const int nwg  = gx * gridDim.y;
    flat = (flat & 7) * (nwg >> 3) + (flat >> 3);   // XCD-chunked, bijective (nwg%8==0)
    const int bn   = flat % gx, bm = flat / gx;
    const int row0 = bm * BM, col0 = bn * BN;
    const int wid  = tid >> 6, lane = tid & 63;
    const int wr   = wid >> 1, wc = wid & 1;
    const int lr   = lane & 15, lg = lane >> 4;

    const int lrow = lane >> 2;           // 0..15 within 16-row chunk
    const int lcol = (lane & 3) * 8;      // 0,8,16,24

    f32x4 acc[4][4] = {};

    for (int k0 = 0; k0 < K; k0 += BK) {
        #pragma unroll
        for (int it = 0; it < 2; ++it) {
            const int c = wid * 2 + it;                     // 0..7
            const int r = c * 16 + lrow;
            gload16(&A [(size_t)(row0 + r) * K + k0 + lcol], &As[c * 512]);
            gload16(&Bt[(size_t)(col0 + r) * K + k0 + lcol], &Bs[c * 512]);
        }
        __syncthreads();

        bf16x8 bfr[4];
        #pragma unroll
        for (int n = 0; n < 4; ++n)
            bfr[n] = *(const bf16x8*)&Bs[(wc * 64 + n * 16 + lr) * BK + lg * 8];
        #pragma unroll
        for (int m = 0; m < 4; ++m) {
            bf16x8 a = *(const bf16x8*)&As[(wr * 64 + m * 16 + lr) * BK + lg * 8];
            #pragma unroll
            for (int n = 0; n < 4; ++n)
                acc[m][n] = __builtin_amdgcn_mfma_f32_16x16x32_bf16(a, bfr[n], acc[m][n], 0, 0, 0);
        }
        __syncthreads();
    }

    if (MODE == 2 && col0 >= 2048) {
        // V block: transposed 8B stores (4 consecutive tokens per fragment)
        #pragma unroll
        for (int m = 0; m < 4; ++m) {
            int rowb = row0 + wr * 64 + m * 16 + lg * 4;
            #pragma unroll
            for (int n = 0; n < 4; ++n) {
                int e = col0 - 2048 + wc * 64 + n * 16 + lr;
                uint_t lo = (uint_t)f2bfu(acc[m][n][0]) | ((uint_t)f2bfu(acc[m][n][1]) << 16);
                uint_t hi = (uint_t)f2bfu(acc[m][n][2]) | ((uint_t)f2bfu(acc[m][n][3]) << 16);
                *(uint2*)&VtOut[(size_t)e * BT_TOT + rowb] = make_uint2(lo, hi);
            }
        }
    } else {
        const int ostride = (MODE == 2) ? 2048 : N;
        #pragma unroll
        for (int m = 0; m < 4; ++m) {
            int rowb = row0 + wr * 64 + m * 16 + lg * 4;
            #pragma unroll
            for (int n = 0; n < 4; ++n) {
                int col = col0 + wc * 64 + n * 16 + lr;
                #pragma unroll
                for (int i = 0; i < 4; ++i) {
                    if (MODE == 2)
                        ((ushort_t*)Cv)[(size_t)(rowb + i) * ostride + col] = f2bfu(acc[m][n][i]);
                    else
                        ((float*)Cv)[(size_t)(rowb + i) * ostride + col] = acc[m][n][i];
                }
            }
        }
    }
}

// ---------------------------------------------------------------------------
// Causal flash attention, swapped-QK^T 32x32x16 structure.
// ROUND 11: 4 waves x 32 q rows = 128 q rows per block (round-3 geometry,
// skip-branch for fully-masked tiles). 1024 blocks; remap gives each CU one
// (b,h) and balanced bx set {c, c+4, c+8, c+12}. Staging per wave halves.
// global_load_lds double-buffered staging (round-10, no spill possible),
// source-side XOR swizzle, 1 barrier/tile. permlane32_swap (builtin) for
// all half-wave exchanges. exp2-domain softmax (scale*log2e folded into Q).
// ---------------------------------------------------------------------------
__global__ __launch_bounds__(256, 4) void attn_fwd(const ushort_t* __restrict__ qk,
                                                   const ushort_t* __restrict__ vt,
                                                   ushort_t* __restrict__ y) {
    const int flat = blockIdx.x;             // 0..1023
    const int xcd  = flat & 7;
    const int s    = flat >> 3;              // 0..127
    const int bh   = xcd * 8 + (s & 7);      // 0..63  (b*16+h)
    const int bx   = 15 - (s >> 3);          // 15..0 heavy-first
    const int b    = bh >> 4, h = bh & 15;
    const int tid  = threadIdx.x, lane = tid & 63;
    const int wid  = tid >> 6;               // 0..3
    const int i    = lane & 31;              // q column within warp tile
    const int hh   = lane >> 5;              // k-half selector
    const int bT   = b * T_SEQ;

    // linear [64 rows][64 cols] bf16, data chunk-XOR-swizzled: lds[r][c^(r&7)]
    __shared__ __align__(16) ushort_t KsL[2][64 * 64];
    __shared__ __align__(16) ushort_t VlL[2][64 * 64];

    const int q0 = bx * 128 + wid * 32;
    const int qg = q0 + i;

    // Q B-fragments: col=q (lane&31), k=dh = kd*16 + hh*8 + j
    // pre-scaled by 0.125 * log2(e) for exp2-domain softmax
    bf16x8 qf[4];
    {
        const float qsc = 0.18033688011112042f;   // 0.125 * 1.4426950408889634
        const ushort_t* qrow = qk + (size_t)(bT + qg) * 2048 + h * DH;
        #pragma unroll
        for (int kd = 0; kd < 4; ++kd) {
            bf16x8 q = *(const bf16x8*)&qrow[kd * 16 + hh * 8];
            #pragma unroll
            for (int j = 0; j < 8; ++j)
                ((ushort_t*)&q)[j] = f2bfu(__bfloat162float(
                    *(const __hip_bfloat16*)&((ushort_t*)&q)[j]) * qsc);
            qf[kd] = q;
        }
    }

    // staging geometry: lane covers row rg+lr8, source chunk (l&7)^(l>>3)
    const int lr8    = lane >> 3;                       // 0..7
    const int schunk = ((lane & 7) ^ lr8) * 8;          // ushort offset in row
    // wave wid stages row groups wid*16 and wid*16+8 (2 gloads per matrix)

    float m = -1e30f, lsum = 0.f;
    f32x16 o0 = {}, o1 = {};

    const int nt = 2 * bx + 2;               // kv tiles 0..2bx+1

    // ---- prologue: stage tile 0 into buffer 0 ----
    #pragma unroll
    for (int it = 0; it < 2; ++it) {
        const int rg = wid * 16 + it * 8;
        const int r  = rg + lr8;
        gload16(&qk[(size_t)(bT + r) * 2048 + 1024 + h * DH + schunk], &KsL[0][rg * 64]);
        gload16(&vt[(size_t)(h * DH + r) * BT_TOT + bT + schunk],      &VlL[0][rg * 64]);
    }
    __syncthreads();

    for (int t = 0; t < nt; ++t) {
        const int cb = t & 1, nb = cb ^ 1;
        const bool has_next = (t + 1 < nt);
        const int kmin = t * 64;

        // ---- (a) issue next tile's async loads into the other buffer ----
        if (has_next) {
            const int kt = kmin + 64;
            #pragma unroll
            for (int it = 0; it < 2; ++it) {
                const int rg = wid * 16 + it * 8;
                const int r  = rg + lr8;
                gload16(&qk[(size_t)(bT + kt + r) * 2048 + 1024 + h * DH + schunk], &KsL[nb][rg * 64]);
                gload16(&vt[(size_t)(h * DH + r) * BT_TOT + bT + kt + schunk],      &VlL[nb][rg * 64]);
            }
        }

        // tiles entirely above this wave's diagonal: stage + barrier only
        if (kmin <= q0 + 31) {
            // ---- (b) S^T = K * Q^T (reads swizzled: chunk cq ^ (row&7)) ----
            f32x16 st[2] = {};
            __builtin_amdgcn_s_setprio(1);
            #pragma unroll
            for (int kd = 0; kd < 4; ++kd) {
                const int cq = kd * 2 + hh;
                bf16x8 ka0 = *(const bf16x8*)&KsL[cb][i * 64        + ((cq ^ (i & 7)) * 8)];
                bf16x8 ka1 = *(const bf16x8*)&KsL[cb][(32 + i) * 64 + ((cq ^ (i & 7)) * 8)];
                st[0] = __builtin_amdgcn_mfma_f32_32x32x16_bf16(ka0, qf[kd], st[0], 0, 0, 0);
                st[1] = __builtin_amdgcn_mfma_f32_32x32x16_bf16(ka1, qf[kd], st[1], 0, 0, 0);
            }
            __builtin_amdgcn_s_setprio(0);

            // ---- (c) mask + row max + online softmax (defer-max, exp2) ----
            const bool needmask = (kmin + 63) > q0;
            float pm = -1e30f;
            #pragma unroll
            for (int g = 0; g < 2; ++g) {
                #pragma unroll
                for (int r = 0; r < 16; ++r) {
                    float v = st[g][r];
                    if (needmask) {
                        int kv = kmin + g * 32 + (r & 3) + 8 * (r >> 2) + 4 * hh;
                        v = (kv <= qg) ? v : -1e30f;
                        st[g][r] = v;
                    }
                    pm = fmaxf(pm, v);
                }
            }
            pm = halfmax(pm);

            if (!__all(pm - m <= 11.5416f)) {      // 8 * log2(e)
                const float mnew = fmaxf(m, pm);
                const float corr = exp2v(m - mnew);
                m = mnew;
                lsum *= corr;
                #pragma unroll
                for (int r = 0; r < 16; ++r) { o0[r] *= corr; o1[r] *= corr; }
            }
            float rs = 0.f;
            #pragma unroll
            for (int g = 0; g < 2; ++g) {
                #pragma unroll
                for (int r = 0; r < 16; ++r) {
                    float p = exp2v(st[g][r] - m);
                    st[g][r] = p;
                    rs += p;
                }
            }
            lsum += halfadd(rs);

            // ---- (d) O^T += V^T * P^T over 4 kv-slices of 16 ----
            #pragma unroll
            for (int ks = 0; ks < 4; ++ks) {
                const int g = ks >> 1, b0 = (ks & 1) * 8;
                uint_t w0 = cvtpk(st[g][b0 + 0], st[g][b0 + 1]);
                uint_t w1 = cvtpk(st[g][b0 + 2], st[g][b0 + 3]);
                uint_t w2 = cvtpk(st[g][b0 + 4], st[g][b0 + 5]);
                uint_t w3 = cvtpk(st[g][b0 + 6], st[g][b0 + 7]);
                plswap(w0, w2);     // w0 -> fr[0], w2 -> fr[2]
                plswap(w1, w3);     // w1 -> fr[1], w3 -> fr[3]
                union { uint_t u[4]; bf16x8 v; } fr;
                fr.u[0] = w0; fr.u[1] = w1; fr.u[2] = w2; fr.u[3] = w3;
                const int ct = ks * 2 + hh;
                bf16x8 va0 = *(const bf16x8*)&VlL[cb][i * 64        + ((ct ^ (i & 7)) * 8)];
                bf16x8 va1 = *(const bf16x8*)&VlL[cb][(32 + i) * 64 + ((ct ^ (i & 7)) * 8)];
                __builtin_amdgcn_s_setprio(1);
                o0 = __builtin_amdgcn_mfma_f32_32x32x16_bf16(va0, fr.v, o0, 0, 0, 0);
                o1 = __builtin_amdgcn_mfma_f32_32x32x16_bf16(va1, fr.v, o1, 0, 0, 0);
                __builtin_amdgcn_s_setprio(0);
            }
        }

        // ---- (e) one barrier: drains async loads after full compute phase ----
        __syncthreads();
    }

    // ---- epilogue: normalize, pack bf16, store ----
    const float inv = 1.f / lsum;
    ushort_t* yrow = y + (size_t)(bT + qg) * (HEADS * DH) + h * DH;
    #pragma unroll
    for (int df = 0; df < 2; ++df) {
        const f32x16 oo = df ? o1 : o0;
        #pragma unroll
        for (int q4 = 0; q4 < 4; ++q4) {
            uint_t w0 = cvtpk(oo[q4 * 4 + 0] * inv, oo[q4 * 4 + 1] * inv);
            uint_t w1 = cvtpk(oo[q4 * 4 + 2] * inv, oo[q4 * 4 + 3] * inv);
            uint2 pk = make_uint2(w0, w1);
            *(uint2*)&yrow[df * 32 + q4 * 8 + hh * 4] = pk;
        }
    }
}

// ---------------------------------------------------------------------------
// launch
// ---------------------------------------------------------------------------
extern "C" void kernel_launch(void* const* d_in, const int* in_sizes, int n_in,
                              void* d_out, int out_size, void* d_ws, size_t ws_size,
                              hipStream_t stream) {
    const float* x     = (const float*)d_in[0];   // [B*T, 1024]
    const float* w_qkv = (const float*)d_in[1];   // [3072, 1024]
    const float* w_out = (const float*)d_in[2];   // [1024, 1024]

    const int BT = BT_TOT;                        // 8192

    char* ws = (char*)d_ws;
    ushort_t* xb  = (ushort_t*)(ws);                       // 16.78 MB
    ushort_t* wqb = (ushort_t*)(ws + 16777216);            //  6.29 MB
    ushort_t* wob = (ushort_t*)(ws + 23068672);            //  2.10 MB
    ushort_t* qkb = (ushort_t*)(ws + 25165824);            // 33.55 MB [token][2048]
    ushort_t* vtb = (ushort_t*)(ws + 58720256);            // 16.78 MB [e][token]
    ushort_t* yb  = (ushort_t*)(ws + 75497472);            // 16.78 MB

    // 1) convert inputs to bf16
    {
        int n4 = (BT * DMODEL) / 4;
        cvt_f32_bf16<<<(n4 + 255) / 256, 256, 0, stream>>>(x, xb, n4);
        n4 = (EQKV * DMODEL) / 4;
        cvt_f32_bf16<<<(n4 + 255) / 256, 256, 0, stream>>>(w_qkv, wqb, n4);
        n4 = (DMODEL * DMODEL) / 4;
        cvt_f32_bf16<<<(n4 + 255) / 256, 256, 0, stream>>>(w_out, wob, n4);
    }

    // 2) qkv = x @ w_qkv^T -> Q,K to qkb (stride 2048); V transposed to vtb
    {
        dim3 grid(EQKV / BN, BT / BM);   // nwg = 1536, %8 == 0
        gemm_bt<2><<<grid, 256, 0, stream>>>(xb, wqb, (void*)qkb, vtb, BT, EQKV, DMODEL);
    }

    // 3) flash attention -> y bf16 [BT][1024]
    {
        attn_fwd<<<1024, 256, 0, stream>>>(qkb, vtb, yb);
    }

    // 4) out = y @ w_out^T   (M=8192, N=1024, K=1024) -> fp32
    {
        dim3 grid(DMODEL / BN, BT / BM); // nwg = 512, %8 == 0
        gemm_bt<0><<<grid, 256, 0, stream>>>(yb, wob, d_out, nullptr, BT, DMODEL, DMODEL);
    }
}